// Round 1
// baseline (14411.273 us; speedup 1.0000x reference)
//
#include <hip/hip_runtime.h>

#define NS 0.2f  // leaky_relu negative slope (PyG GATv2 default)

// ---------- float <-> order-preserving uint (for atomic max on floats) ----------
__device__ __forceinline__ unsigned f2o(float f){
  unsigned u = __float_as_uint(f);
  return (u & 0x80000000u) ? ~u : (u | 0x80000000u);
}
__device__ __forceinline__ float o2f(unsigned u){
  return (u & 0x80000000u) ? __uint_as_float(u & 0x7FFFFFFFu) : __uint_as_float(~u);
}

// ---------- degree + sum of edge attrs per dst ----------
__global__ void k_deg_easum(const int* __restrict__ dst, const float* __restrict__ ea,
                            float* easum, float* deg, int E){
  long total = (long)E * 18;
  long stride = (long)gridDim.x * blockDim.x;
  for(long idx = (long)blockIdx.x * blockDim.x + threadIdx.x; idx < total; idx += stride){
    int e = (int)(idx / 18);
    int k = (int)(idx - (long)e * 18);
    int d = dst[e];
    atomicAdd(&easum[(long)d * 18 + k], ea[idx]);
    if(k == 0) atomicAdd(&deg[d], 1.0f);
  }
}

// easum -> ea_mean (in place)
__global__ void k_ea_mean(float* easum, const float* __restrict__ deg, int n){
  long total = (long)n * 18;
  long stride = (long)gridDim.x * blockDim.x;
  for(long idx = (long)blockIdx.x * blockDim.x + threadIdx.x; idx < total; idx += stride){
    int i = (int)(idx / 18);
    easum[idx] /= fmaxf(deg[i], 1.0f);
  }
}

// xl = x @ Wl^T + bl ; xr = x @ Wr^T + br
__global__ void k_lin2(const float* __restrict__ x, int fin,
                       const float* __restrict__ Wl, const float* __restrict__ bl,
                       const float* __restrict__ Wr, const float* __restrict__ br,
                       float* xl, float* xr, long n, int fout){
  long total = n * fout;
  long stride = (long)gridDim.x * blockDim.x;
  for(long idx = (long)blockIdx.x * blockDim.x + threadIdx.x; idx < total; idx += stride){
    int f = (int)(idx % fout);
    long i = idx / fout;
    const float* xrow = x + i * fin;
    const float* wl = Wl + (long)f * fin;
    const float* wr = Wr + (long)f * fin;
    float a1 = bl[f], a2 = br[f];
    for(int k = 0; k < fin; k++){
      float xv = xrow[k];
      a1 += wl[k] * xv;
      a2 += wr[k] * xv;
    }
    xl[idx] = a1; xr[idx] = a2;
  }
}

// generic y = x @ W^T + b, optional relu
__global__ void k_lin(const float* __restrict__ x, int fin,
                      const float* __restrict__ W, const float* __restrict__ b,
                      float* y, long n, int fout, int dorelu){
  long total = n * fout;
  long stride = (long)gridDim.x * blockDim.x;
  for(long idx = (long)blockIdx.x * blockDim.x + threadIdx.x; idx < total; idx += stride){
    int f = (int)(idx % fout);
    long i = idx / fout;
    const float* xrow = x + i * fin;
    const float* wrow = W + (long)f * fin;
    float a = b[f];
    for(int k = 0; k < fin; k++) a += wrow[k] * xrow[k];
    y[idx] = dorelu ? fmaxf(a, 0.0f) : a;
  }
}

// per-edge logits + running segment max (ordered-uint atomicMax)
__global__ void k_edge_logits(const int* __restrict__ src, const int* __restrict__ dst,
                              const float* __restrict__ ea,
                              const float* __restrict__ xl, const float* __restrict__ xr,
                              const float* __restrict__ We, const float* __restrict__ att,
                              float* logits, unsigned* mord, int E, int F){
  int stride = gridDim.x * blockDim.x;
  for(int e = blockIdx.x * blockDim.x + threadIdx.x; e < E; e += stride){
    int s = src[e], d = dst[e];
    float eav[18];
    #pragma unroll
    for(int k = 0; k < 18; k++) eav[k] = ea[(long)e * 18 + k];
    const float* xls = xl + (long)s * F;
    const float* xrd = xr + (long)d * F;
    float acc = 0.0f;
    for(int f = 0; f < F; f++){
      const float* wrow = We + f * 18;
      float t = xls[f] + xrd[f];
      #pragma unroll
      for(int k = 0; k < 18; k++) t += wrow[k] * eav[k];
      t = (t > 0.0f) ? t : NS * t;
      acc += att[f] * t;
    }
    logits[e] = acc;
    atomicMax(&mord[d], f2o(acc));
  }
}

// self-loop logits (ea = ea_mean row), also feeds segment max
__global__ void k_self_logits(const float* __restrict__ eam,
                              const float* __restrict__ xl, const float* __restrict__ xr,
                              const float* __restrict__ We, const float* __restrict__ att,
                              float* selfl, unsigned* mord, int n, int F){
  int stride = gridDim.x * blockDim.x;
  for(int i = blockIdx.x * blockDim.x + threadIdx.x; i < n; i += stride){
    float eav[18];
    #pragma unroll
    for(int k = 0; k < 18; k++) eav[k] = eam[(long)i * 18 + k];
    const float* xls = xl + (long)i * F;
    const float* xrd = xr + (long)i * F;
    float acc = 0.0f;
    for(int f = 0; f < F; f++){
      const float* wrow = We + f * 18;
      float t = xls[f] + xrd[f];
      #pragma unroll
      for(int k = 0; k < 18; k++) t += wrow[k] * eav[k];
      t = (t > 0.0f) ? t : NS * t;
      acc += att[f] * t;
    }
    selfl[i] = acc;
    atomicMax(&mord[i], f2o(acc));
  }
}

__global__ void k_exp_edges(const int* __restrict__ dst, float* logits,
                            const unsigned* __restrict__ mord, float* denom, int E){
  int stride = gridDim.x * blockDim.x;
  for(int e = blockIdx.x * blockDim.x + threadIdx.x; e < E; e += stride){
    int d = dst[e];
    float p = expf(logits[e] - o2f(mord[d]));
    logits[e] = p;
    atomicAdd(&denom[d], p);
  }
}

__global__ void k_exp_self(float* selfl, const unsigned* __restrict__ mord,
                           float* denom, int n){
  int stride = gridDim.x * blockDim.x;
  for(int i = blockIdx.x * blockDim.x + threadIdx.x; i < n; i += stride){
    float p = expf(selfl[i] - o2f(mord[i]));
    selfl[i] = p;
    atomicAdd(&denom[i], p);
  }
}

__global__ void k_norm_edges(const int* __restrict__ dst, float* logits,
                             const float* __restrict__ denom, int E){
  int stride = gridDim.x * blockDim.x;
  for(int e = blockIdx.x * blockDim.x + threadIdx.x; e < E; e += stride){
    logits[e] /= denom[dst[e]];
  }
}

// out[dst] += alpha * xl[src]  (edge-parallel scatter)
__global__ void k_agg(const int* __restrict__ src, const int* __restrict__ dst,
                      const float* __restrict__ alpha, const float* __restrict__ xl,
                      float* out, int E, int F){
  long total = (long)E * F;
  long stride = (long)gridDim.x * blockDim.x;
  for(long idx = (long)blockIdx.x * blockDim.x + threadIdx.x; idx < total; idx += stride){
    int e = (int)(idx / F);
    int f = (int)(idx - (long)e * F);
    atomicAdd(&out[(long)dst[e] * F + f], alpha[e] * xl[(long)src[e] * F + f]);
  }
}

// finalize: add self-loop term + bias, optional relu
__global__ void k_agg_self(const float* __restrict__ selfp, const float* __restrict__ denom,
                           const float* __restrict__ xl, const float* __restrict__ b,
                           float* out, long n, int F, int dorelu){
  long total = n * F;
  long stride = (long)gridDim.x * blockDim.x;
  for(long idx = (long)blockIdx.x * blockDim.x + threadIdx.x; idx < total; idx += stride){
    long i = idx / F;
    int f = (int)(idx % F);
    float a = out[idx] + (selfp[i] / denom[i]) * xl[idx] + b[f];
    out[idx] = dorelu ? fmaxf(a, 0.0f) : a;
  }
}

// segment mean-pool: accumulate
__global__ void k_pool_seg(const float* __restrict__ h, const int* __restrict__ seg,
                           float* y, float* cnt, long n, int F){
  long total = n * F;
  long stride = (long)gridDim.x * blockDim.x;
  for(long idx = (long)blockIdx.x * blockDim.x + threadIdx.x; idx < total; idx += stride){
    long i = idx / F;
    int f = (int)(idx % F);
    int r = seg[i];
    atomicAdd(&y[(long)r * F + f], h[idx]);
    if(f == 0) atomicAdd(&cnt[r], 1.0f);
  }
}

__global__ void k_pool_div(float* y, const float* __restrict__ cnt, long R, int F){
  long total = R * F;
  long stride = (long)gridDim.x * blockDim.x;
  for(long idx = (long)blockIdx.x * blockDim.x + threadIdx.x; idx < total; idx += stride){
    y[idx] /= fmaxf(cnt[idx / F], 1.0f);
  }
}

// sum over ALL rows (batch is all zeros -> single segment) via LDS accumulation
__global__ void k_pool_all(const float* __restrict__ g, float* xp, long total, int F){
  __shared__ float s[128];
  for(int j = threadIdx.x; j < F; j += blockDim.x) s[j] = 0.0f;
  __syncthreads();
  long stride = (long)gridDim.x * blockDim.x;
  for(long idx = (long)blockIdx.x * blockDim.x + threadIdx.x; idx < total; idx += stride){
    atomicAdd(&s[(int)(idx % F)], g[idx]);
  }
  __syncthreads();
  for(int j = threadIdx.x; j < F; j += blockDim.x){
    float v = s[j];
    if(v != 0.0f) atomicAdd(&xp[j], v);
  }
}

// v[e] = (1/N) * sum_d xp[d] * bilW[d*100+e]
__global__ void k_bil_v(const float* __restrict__ xp, const float* __restrict__ Wb,
                        float* v, float inv_n){
  int e = threadIdx.x;
  if(e < 100){
    float a = 0.0f;
    for(int d = 0; d < 100; d++) a += xp[d] * Wb[d * 100 + e];
    v[e] = a * inv_n;
  }
}

// out[r] = bilb + sum_e v[e] * y[r*100+e]
__global__ void k_bil_out(const float* __restrict__ v, const float* __restrict__ y,
                          const float* __restrict__ bilb, float* out, int R){
  int r = blockIdx.x * blockDim.x + threadIdx.x;
  if(r < R){
    float a = 0.0f;
    const float* yr = y + (long)r * 100;
    for(int e = 0; e < 100; e++) a += v[e] * yr[e];
    out[r] = a + bilb[0];
  }
}

// ------------------------------------------------------------------
static inline int nblk(long n){
  long b = (n + 255) / 256;
  if(b > 20480) b = 20480;
  if(b < 1) b = 1;
  return (int)b;
}

struct GatParams { const float *Wl,*bl,*Wr,*br,*We,*att,*b; };

static void run_gatv2(const float* x, int fin, int fout, int n,
                      const int* src, const int* dst, const float* ea, int E,
                      GatParams P, float* out, int dorelu,
                      float* xl, float* xr, float* easum, float* deg,
                      unsigned* mord, float* denom, float* selfl, float* logits,
                      hipStream_t stream){
  hipMemsetAsync(easum, 0, (size_t)n * 18 * 4, stream);
  hipMemsetAsync(deg,   0, (size_t)n * 4, stream);
  hipMemsetAsync(mord,  0, (size_t)n * 4, stream);
  hipMemsetAsync(denom, 0, (size_t)n * 4, stream);
  hipMemsetAsync(out,   0, (size_t)n * fout * 4, stream);

  k_deg_easum<<<nblk((long)E * 18), 256, 0, stream>>>(dst, ea, easum, deg, E);
  k_ea_mean  <<<nblk((long)n * 18), 256, 0, stream>>>(easum, deg, n);
  k_lin2     <<<nblk((long)n * fout), 256, 0, stream>>>(x, fin, P.Wl, P.bl, P.Wr, P.br, xl, xr, n, fout);
  k_edge_logits<<<nblk(E), 256, 0, stream>>>(src, dst, ea, xl, xr, P.We, P.att, logits, mord, E, fout);
  k_self_logits<<<nblk(n), 256, 0, stream>>>(easum, xl, xr, P.We, P.att, selfl, mord, n, fout);
  k_exp_edges<<<nblk(E), 256, 0, stream>>>(dst, logits, mord, denom, E);
  k_exp_self <<<nblk(n), 256, 0, stream>>>(selfl, mord, denom, n);
  k_norm_edges<<<nblk(E), 256, 0, stream>>>(dst, logits, denom, E);
  k_agg      <<<nblk((long)E * fout), 256, 0, stream>>>(src, dst, logits, xl, out, E, fout);
  k_agg_self <<<nblk((long)n * fout), 256, 0, stream>>>(selfl, denom, xl, P.b, out, n, fout, dorelu);
}

extern "C" void kernel_launch(void* const* d_in, const int* in_sizes, int n_in,
                              void* d_out, int out_size, void* d_ws, size_t ws_size,
                              hipStream_t stream){
  const float* x        = (const float*)d_in[0];
  const float* ea       = (const float*)d_in[1];
  const float* rx       = (const float*)d_in[2];
  const float* rea      = (const float*)d_in[3];
  GatParams g0{ (const float*)d_in[4],  (const float*)d_in[5],  (const float*)d_in[6],
                (const float*)d_in[7],  (const float*)d_in[8],  (const float*)d_in[9],
                (const float*)d_in[10] };
  GatParams g1{ (const float*)d_in[11], (const float*)d_in[12], (const float*)d_in[13],
                (const float*)d_in[14], (const float*)d_in[15], (const float*)d_in[16],
                (const float*)d_in[17] };
  GatParams g2{ (const float*)d_in[18], (const float*)d_in[19], (const float*)d_in[20],
                (const float*)d_in[21], (const float*)d_in[22], (const float*)d_in[23],
                (const float*)d_in[24] };
  const float* lin_W = (const float*)d_in[25]; const float* lin_b = (const float*)d_in[26];
  const float* f1_W  = (const float*)d_in[27]; const float* f1_b  = (const float*)d_in[28];
  const float* f2_W  = (const float*)d_in[29]; const float* f2_b  = (const float*)d_in[30];
  const float* f3_W  = (const float*)d_in[31]; const float* f3_b  = (const float*)d_in[32];
  const float* bilW  = (const float*)d_in[33]; const float* bilb  = (const float*)d_in[34];
  const int* ei  = (const int*)d_in[35];
  // d_in[36] = batch (all zeros; single segment -> handled as global mean)
  const int* rei = (const int*)d_in[37];
  const int* rb  = (const int*)d_in[38];
  // d_in[39] = n_rules (== out_size)

  const int N  = in_sizes[0] / 16;
  const int E  = in_sizes[1] / 18;
  const int NR = in_sizes[2] / 16;
  const int ER = in_sizes[3] / 18;
  const int R  = out_size;

  float* W = (float*)d_ws;
  size_t off = 0;
  auto alloc = [&](size_t nf){ float* p = W + off; off += nf; return p; };

  // --- small persistent head ---
  float* y0  = alloc((size_t)R * 400);
  float* y1  = alloc((size_t)R * 200);
  float* y2  = alloc((size_t)R * 100);
  float* y3  = alloc((size_t)R * 100);
  float* cnt = alloc(R);
  float* xp  = alloc(128);
  float* v   = alloc(128);
  const size_t arena = off;

  // ================= rule path =================
  {
    off = arena;
    float* h1 = alloc((size_t)NR * 100);
    float* h2 = alloc((size_t)NR * 200);
    float* xl = alloc((size_t)NR * 200);
    float* xr = alloc((size_t)NR * 200);
    float* easum = alloc((size_t)NR * 18);
    float* deg   = alloc(NR);
    unsigned* mord = (unsigned*)alloc(NR);
    float* denom = alloc(NR);
    float* selfl = alloc(NR);
    float* logits = alloc(ER);
    const int* rsrc = rei; const int* rdst = rei + ER;

    run_gatv2(rx, 16, 100, NR, rsrc, rdst, rea, ER, g1, h1, 1,
              xl, xr, easum, deg, mord, denom, selfl, logits, stream);
    run_gatv2(h1, 100, 200, NR, rsrc, rdst, rea, ER, g2, h2, 1,
              xl, xr, easum, deg, mord, denom, selfl, logits, stream);

    float* hlin = xl;  // NR*400 fits in xl+xr region
    k_lin<<<nblk((long)NR * 400), 256, 0, stream>>>(h2, 200, lin_W, lin_b, hlin, NR, 400, 0);

    hipMemsetAsync(y0, 0, (size_t)R * 400 * 4, stream);
    hipMemsetAsync(cnt, 0, (size_t)R * 4, stream);
    k_pool_seg<<<nblk((long)NR * 400), 256, 0, stream>>>(hlin, rb, y0, cnt, NR, 400);
    k_pool_div<<<nblk((long)R * 400), 256, 0, stream>>>(y0, cnt, R, 400);

    k_lin<<<nblk((long)R * 200), 256, 0, stream>>>(y0, 400, f1_W, f1_b, y1, R, 200, 1);
    k_lin<<<nblk((long)R * 100), 256, 0, stream>>>(y1, 200, f2_W, f2_b, y2, R, 100, 1);
    k_lin<<<nblk((long)R * 100), 256, 0, stream>>>(y2, 100, f3_W, f3_b, y3, R, 100, 0);
  }

  // ================= data path =================
  {
    off = arena;
    float* g  = alloc((size_t)N * 100);
    float* xl = alloc((size_t)N * 100);
    float* xr = alloc((size_t)N * 100);
    float* easum = alloc((size_t)N * 18);
    float* deg   = alloc(N);
    unsigned* mord = (unsigned*)alloc(N);
    float* denom = alloc(N);
    float* selfl = alloc(N);
    float* logits = alloc(E);
    const int* srcp = ei; const int* dstp = ei + E;

    run_gatv2(x, 16, 100, N, srcp, dstp, ea, E, g0, g, 0,
              xl, xr, easum, deg, mord, denom, selfl, logits, stream);

    hipMemsetAsync(xp, 0, 128 * 4, stream);
    k_pool_all<<<nblk((long)N * 100), 256, 0, stream>>>(g, xp, (long)N * 100, 100);
    k_bil_v<<<1, 128, 0, stream>>>(xp, bilW, v, 1.0f / (float)N);
    k_bil_out<<<(R + 127) / 128, 128, 0, stream>>>(v, y3, bilb, (float*)d_out, R);
  }
}

// Round 2
// 2190.000 us; speedup vs baseline: 6.5805x; 6.5805x over previous
//
#include <hip/hip_runtime.h>

#define NS 0.2f  // leaky_relu negative slope

// ===================== CSR construction =====================
__global__ void k_deg(const int* __restrict__ dst, int* degi, int E){
  int stride = gridDim.x * blockDim.x;
  for(int e = blockIdx.x * blockDim.x + threadIdx.x; e < E; e += stride)
    atomicAdd(&degi[dst[e]], 1);
}

__device__ __forceinline__ int wave_iscan(int v, int lane){
  #pragma unroll
  for(int o = 1; o < 64; o <<= 1){
    int t = __shfl_up(v, o);
    if(lane >= o) v += t;
  }
  return v;
}

// single-block exclusive scan (chunked, wave-level shfl scan)
__global__ void k_scan(const int* __restrict__ deg, int* __restrict__ rowoff, int n){
  __shared__ int wsum[16];
  __shared__ int carry_s;
  const int lane = threadIdx.x & 63;
  const int w = threadIdx.x >> 6;
  if(threadIdx.x == 0) carry_s = 0;
  __syncthreads();
  for(int base = 0; base < n; base += 1024){
    int idx = base + (int)threadIdx.x;
    int v = (idx < n) ? deg[idx] : 0;
    int inc = wave_iscan(v, lane);
    if(lane == 63) wsum[w] = inc;
    __syncthreads();
    if(w == 0){
      int s = (lane < 16) ? wsum[lane] : 0;
      s = wave_iscan(s, lane);
      if(lane < 16) wsum[lane] = s;
    }
    __syncthreads();
    int woff = (w > 0) ? wsum[w - 1] : 0;
    int total = wsum[15];
    if(idx < n) rowoff[idx] = carry_s + woff + inc - v;
    __syncthreads();
    if(threadIdx.x == 0) carry_s += total;
    __syncthreads();
  }
  if(threadIdx.x == 0) rowoff[n] = carry_s;
}

__global__ void k_fill(const int* __restrict__ dst, int* pos, int* eidx, int E){
  int stride = gridDim.x * blockDim.x;
  for(int e = blockIdx.x * blockDim.x + threadIdx.x; e < E; e += stride){
    int slot = atomicAdd(&pos[dst[e]], 1);
    eidx[slot] = e;
  }
}

// ===================== tiled GEMM: C = A @ W^T + b =====================
// A: n x K,  W: M x K (row-major),  C: n x M
#define BM 64
#define BN 64
#define BK 16
__global__ __launch_bounds__(256) void k_gemm(
    const float* __restrict__ A, const float* __restrict__ W,
    const float* __restrict__ b, float* __restrict__ C,
    int n, int K, int M, int dorelu)
{
  __shared__ float As[BM][BK + 1];
  __shared__ float Bs[BN][BK + 1];
  const int bi = blockIdx.x * BM;
  const int bj = blockIdx.y * BN;
  const int tid = threadIdx.x;
  const int tr = tid / 16, tc = tid % 16;
  float acc[4][4] = {};
  for(int k0 = 0; k0 < K; k0 += BK){
    for(int l = tid; l < BM * BK; l += 256){
      int r = l / BK, c = l % BK;
      int gr = bi + r, gc = k0 + c;
      As[r][c] = (gr < n && gc < K) ? A[(long)gr * K + gc] : 0.0f;
    }
    for(int l = tid; l < BN * BK; l += 256){
      int r = l / BK, c = l % BK;
      int gr = bj + r, gc = k0 + c;
      Bs[r][c] = (gr < M && gc < K) ? W[(long)gr * K + gc] : 0.0f;
    }
    __syncthreads();
    #pragma unroll
    for(int kk = 0; kk < BK; ++kk){
      float av[4], bv[4];
      #pragma unroll
      for(int r = 0; r < 4; r++) av[r] = As[tr * 4 + r][kk];
      #pragma unroll
      for(int c = 0; c < 4; c++) bv[c] = Bs[tc * 4 + c][kk];
      #pragma unroll
      for(int r = 0; r < 4; r++)
        #pragma unroll
        for(int c = 0; c < 4; c++) acc[r][c] += av[r] * bv[c];
    }
    __syncthreads();
  }
  for(int r = 0; r < 4; r++){
    int gr = bi + tr * 4 + r;
    if(gr >= n) continue;
    for(int c = 0; c < 4; c++){
      int gc = bj + tc * 4 + c;
      if(gc >= M) continue;
      float val = acc[r][c] + b[gc];
      C[(long)gr * M + gc] = dorelu ? fmaxf(val, 0.0f) : val;
    }
  }
}

static void gemm_launch(const float* A, const float* W, const float* b, float* C,
                        int n, int K, int M, int relu, hipStream_t s){
  dim3 grid((n + BM - 1) / BM, (M + BN - 1) / BN);
  k_gemm<<<grid, 256, 0, s>>>(A, W, b, C, n, K, M, relu);
}

// ===================== fused GATv2 node kernel =====================
// one wave (64 lanes) per node; online softmax; zero atomics.
// out[i] = sum_e alpha_e * xl[src_e] + alpha_self * xl[i] + bias
__global__ __launch_bounds__(256) void k_gat_node(
    const float* __restrict__ xl, const float* __restrict__ xr,
    const float* __restrict__ ea, const int* __restrict__ src,
    const int* __restrict__ rowoff, const int* __restrict__ eidx,
    const float* __restrict__ We, const float* __restrict__ att,
    const float* __restrict__ bias, float* __restrict__ out,
    int n, int F, int dorelu)
{
  const int lane = threadIdx.x & 63;
  const int wid = threadIdx.x >> 6;
  const int i = blockIdx.x * 4 + wid;
  __shared__ float eam_s[4][18];
  const bool active = (i < n);
  int r0 = 0, r1 = 0;
  if(active){ r0 = rowoff[i]; r1 = rowoff[i + 1]; }
  // ea_mean for the self-loop (lane k sums feature k over incident edges)
  if(active && lane < 18){
    float s = 0.0f;
    for(int p = r0; p < r1; ++p) s += ea[(long)eidx[p] * 18 + lane];
    eam_s[wid][lane] = s / fmaxf((float)(r1 - r0), 1.0f);
  }
  __syncthreads();
  if(!active) return;

  // hoist per-node rows
  float xrv[4], attv[4];
  {
    int j = 0;
    for(int f = lane; f < F; f += 64, ++j){
      xrv[j] = xr[(long)i * F + f];
      attv[j] = att[f];
    }
  }

  float m = -3.4e38f;
  float denom = 0.0f;
  float acc[4] = {0.0f, 0.0f, 0.0f, 0.0f};

  // ---- incident edges (online softmax + aggregate) ----
  for(int p = r0; p < r1; ++p){
    int e = eidx[p];
    int s = src[e];
    float eav[18];
    #pragma unroll
    for(int k = 0; k < 18; k++) eav[k] = ea[(long)e * 18 + k];
    float a = 0.0f;
    float xlv[4];
    int j = 0;
    for(int f = lane; f < F; f += 64, ++j){
      float xv = xl[(long)s * F + f];
      xlv[j] = xv;
      float t = xv + xrv[j];
      const float* w = We + f * 18;
      #pragma unroll
      for(int k = 0; k < 18; k++) t = fmaf(w[k], eav[k], t);
      t = (t > 0.0f) ? t : NS * t;
      a = fmaf(attv[j], t, a);
    }
    #pragma unroll
    for(int o = 32; o; o >>= 1) a += __shfl_xor(a, o);
    if(a > m){  // wave-uniform branch
      float sc = expf(m - a);
      denom *= sc;
      #pragma unroll
      for(int jj = 0; jj < 4; jj++) acc[jj] *= sc;
      m = a;
    }
    float pe = expf(a - m);
    denom += pe;
    j = 0;
    for(int f = lane; f < F; f += 64, ++j) acc[j] += pe * xlv[j];
  }

  // ---- self loop (ea = ea_mean) ----
  {
    float a = 0.0f;
    float xlv[4];
    int j = 0;
    for(int f = lane; f < F; f += 64, ++j){
      float xv = xl[(long)i * F + f];
      xlv[j] = xv;
      float t = xv + xrv[j];
      const float* w = We + f * 18;
      #pragma unroll
      for(int k = 0; k < 18; k++) t = fmaf(w[k], eam_s[wid][k], t);
      t = (t > 0.0f) ? t : NS * t;
      a = fmaf(attv[j], t, a);
    }
    #pragma unroll
    for(int o = 32; o; o >>= 1) a += __shfl_xor(a, o);
    if(a > m){
      float sc = expf(m - a);
      denom *= sc;
      #pragma unroll
      for(int jj = 0; jj < 4; jj++) acc[jj] *= sc;
      m = a;
    }
    float pe = expf(a - m);
    denom += pe;
    j = 0;
    for(int f = lane; f < F; f += 64, ++j) acc[j] += pe * xlv[j];
  }

  // ---- write out ----
  {
    float inv = 1.0f / denom;
    int j = 0;
    for(int f = lane; f < F; f += 64, ++j){
      float o = acc[j] * inv + bias[f];
      out[(long)i * F + f] = dorelu ? fmaxf(o, 0.0f) : o;
    }
  }
}

// ===================== rule pooling (rule_batch is sorted) =====================
__global__ void k_rule_starts(const int* __restrict__ rb, int* starts, int NR, int R){
  int r = blockIdx.x * blockDim.x + threadIdx.x;
  if(r > R) return;
  if(r == R){ starts[R] = NR; return; }
  int lo = 0, hi = NR;
  while(lo < hi){ int mid = (lo + hi) >> 1; if(rb[mid] < r) lo = mid + 1; else hi = mid; }
  starts[r] = lo;
}

__global__ void k_pool_rules(const float* __restrict__ h, const int* __restrict__ starts,
                             float* __restrict__ y, int R, int F){
  long idx = (long)blockIdx.x * blockDim.x + threadIdx.x;
  long total = (long)R * F;
  if(idx >= total) return;
  int r = (int)(idx / F);
  int f = (int)(idx % F);
  int s0 = starts[r], s1 = starts[r + 1];
  float a = 0.0f;
  for(int i = s0; i < s1; i++) a += h[(long)i * F + f];
  y[idx] = a / fmaxf((float)(s1 - s0), 1.0f);
}

// ===================== data-path global mean + bilinear =====================
__global__ void k_pool_all(const float* __restrict__ g, float* xp, long total, int F){
  __shared__ float s[128];
  for(int j = threadIdx.x; j < F; j += blockDim.x) s[j] = 0.0f;
  __syncthreads();
  long stride = (long)gridDim.x * blockDim.x;
  for(long idx = (long)blockIdx.x * blockDim.x + threadIdx.x; idx < total; idx += stride){
    atomicAdd(&s[(int)(idx % F)], g[idx]);
  }
  __syncthreads();
  for(int j = threadIdx.x; j < F; j += blockDim.x){
    float v = s[j];
    if(v != 0.0f) atomicAdd(&xp[j], v);
  }
}

__global__ void k_bil_v(const float* __restrict__ xp, const float* __restrict__ Wb,
                        float* v, float inv_n){
  int e = threadIdx.x;
  if(e < 100){
    float a = 0.0f;
    for(int d = 0; d < 100; d++) a += xp[d] * Wb[d * 100 + e];
    v[e] = a * inv_n;
  }
}

__global__ void k_bil_out(const float* __restrict__ v, const float* __restrict__ y,
                          const float* __restrict__ bilb, float* out, int R){
  int r = blockIdx.x * blockDim.x + threadIdx.x;
  if(r < R){
    float a = 0.0f;
    const float* yr = y + (long)r * 100;
    for(int e = 0; e < 100; e++) a += v[e] * yr[e];
    out[r] = a + bilb[0];
  }
}

// ------------------------------------------------------------------
static inline int nblk(long n){
  long b = (n + 255) / 256;
  if(b > 20480) b = 20480;
  if(b < 1) b = 1;
  return (int)b;
}

struct GatParams { const float *Wl,*bl,*Wr,*br,*We,*att,*b; };

extern "C" void kernel_launch(void* const* d_in, const int* in_sizes, int n_in,
                              void* d_out, int out_size, void* d_ws, size_t ws_size,
                              hipStream_t stream){
  const float* x        = (const float*)d_in[0];
  const float* ea       = (const float*)d_in[1];
  const float* rx       = (const float*)d_in[2];
  const float* rea      = (const float*)d_in[3];
  GatParams g0{ (const float*)d_in[4],  (const float*)d_in[5],  (const float*)d_in[6],
                (const float*)d_in[7],  (const float*)d_in[8],  (const float*)d_in[9],
                (const float*)d_in[10] };
  GatParams g1{ (const float*)d_in[11], (const float*)d_in[12], (const float*)d_in[13],
                (const float*)d_in[14], (const float*)d_in[15], (const float*)d_in[16],
                (const float*)d_in[17] };
  GatParams g2{ (const float*)d_in[18], (const float*)d_in[19], (const float*)d_in[20],
                (const float*)d_in[21], (const float*)d_in[22], (const float*)d_in[23],
                (const float*)d_in[24] };
  const float* lin_W = (const float*)d_in[25]; const float* lin_b = (const float*)d_in[26];
  const float* f1_W  = (const float*)d_in[27]; const float* f1_b  = (const float*)d_in[28];
  const float* f2_W  = (const float*)d_in[29]; const float* f2_b  = (const float*)d_in[30];
  const float* f3_W  = (const float*)d_in[31]; const float* f3_b  = (const float*)d_in[32];
  const float* bilW  = (const float*)d_in[33]; const float* bilb  = (const float*)d_in[34];
  const int* ei  = (const int*)d_in[35];
  const int* rei = (const int*)d_in[37];
  const int* rb  = (const int*)d_in[38];

  const int N  = in_sizes[0] / 16;
  const int E  = in_sizes[1] / 18;
  const int NR = in_sizes[2] / 16;
  const int ER = in_sizes[3] / 18;
  const int R  = out_size;

  float* Wf = (float*)d_ws;
  size_t off = 0;
  auto alloc  = [&](size_t nf){ float* p = Wf + off; off += nf; return p; };
  auto alloci = [&](size_t ni){ int* p = (int*)(Wf + off); off += ni; return p; };

  // persistent head
  float* y0 = alloc((size_t)R * 400);
  float* y1 = alloc((size_t)R * 200);
  float* y2 = alloc((size_t)R * 100);
  float* y3 = alloc((size_t)R * 100);
  float* xp = alloc(128);
  float* v  = alloc(128);
  int* starts = alloci(R + 1);
  const size_t arena = off;

  // ================= rule path =================
  {
    off = arena;
    float* h1 = alloc((size_t)NR * 100);
    float* h2 = alloc((size_t)NR * 200);
    float* xl = alloc((size_t)NR * 200);
    float* xr = alloc((size_t)NR * 200);
    int* rowoff = alloci(NR + 1);
    int* degi   = alloci(NR);
    int* pos    = alloci(NR);
    int* eidx   = alloci(ER);
    const int* rsrc = rei; const int* rdst = rei + ER;

    // CSR (shared by both rule GAT layers)
    hipMemsetAsync(degi, 0, (size_t)NR * 4, stream);
    k_deg<<<nblk(ER), 256, 0, stream>>>(rdst, degi, ER);
    k_scan<<<1, 1024, 0, stream>>>(degi, rowoff, NR);
    hipMemcpyAsync(pos, rowoff, (size_t)NR * 4, hipMemcpyDeviceToDevice, stream);
    k_fill<<<nblk(ER), 256, 0, stream>>>(rdst, pos, eidx, ER);

    // gat1: 16 -> 100, relu
    gemm_launch(rx, g1.Wl, g1.bl, xl, NR, 16, 100, 0, stream);
    gemm_launch(rx, g1.Wr, g1.br, xr, NR, 16, 100, 0, stream);
    k_gat_node<<<(NR + 3) / 4, 256, 0, stream>>>(xl, xr, rea, rsrc, rowoff, eidx,
                                                 g1.We, g1.att, g1.b, h1, NR, 100, 1);
    // gat2: 100 -> 200, relu
    gemm_launch(h1, g2.Wl, g2.bl, xl, NR, 100, 200, 0, stream);
    gemm_launch(h1, g2.Wr, g2.br, xr, NR, 100, 200, 0, stream);
    k_gat_node<<<(NR + 3) / 4, 256, 0, stream>>>(xl, xr, rea, rsrc, rowoff, eidx,
                                                 g2.We, g2.att, g2.b, h2, NR, 200, 1);
    // lin 200 -> 400 (reuse xl+xr region: NR*400 floats)
    float* hlin = xl;
    gemm_launch(h2, lin_W, lin_b, hlin, NR, 200, 400, 0, stream);

    // mean-pool per rule (rule_batch sorted -> segment gather)
    k_rule_starts<<<(R + 256) / 256, 256, 0, stream>>>(rb, starts, NR, R);
    k_pool_rules<<<nblk((long)R * 400), 256, 0, stream>>>(hlin, starts, y0, R, 400);

    gemm_launch(y0, f1_W, f1_b, y1, R, 400, 200, 1, stream);
    gemm_launch(y1, f2_W, f2_b, y2, R, 200, 100, 1, stream);
    gemm_launch(y2, f3_W, f3_b, y3, R, 100, 100, 0, stream);
  }

  // ================= data path =================
  {
    off = arena;
    float* g  = alloc((size_t)N * 100);
    float* xl = alloc((size_t)N * 100);
    float* xr = alloc((size_t)N * 100);
    int* rowoff = alloci((size_t)N + 1);
    int* degi   = alloci(N);
    int* pos    = alloci(N);
    int* eidx   = alloci(E);
    const int* srcp = ei; const int* dstp = ei + E;

    hipMemsetAsync(degi, 0, (size_t)N * 4, stream);
    k_deg<<<nblk(E), 256, 0, stream>>>(dstp, degi, E);
    k_scan<<<1, 1024, 0, stream>>>(degi, rowoff, N);
    hipMemcpyAsync(pos, rowoff, (size_t)N * 4, hipMemcpyDeviceToDevice, stream);
    k_fill<<<nblk(E), 256, 0, stream>>>(dstp, pos, eidx, E);

    gemm_launch(x, g0.Wl, g0.bl, xl, N, 16, 100, 0, stream);
    gemm_launch(x, g0.Wr, g0.br, xr, N, 16, 100, 0, stream);
    k_gat_node<<<(N + 3) / 4, 256, 0, stream>>>(xl, xr, ea, srcp, rowoff, eidx,
                                                g0.We, g0.att, g0.b, g, N, 100, 0);

    hipMemsetAsync(xp, 0, 128 * 4, stream);
    k_pool_all<<<nblk((long)N * 100), 256, 0, stream>>>(g, xp, (long)N * 100, 100);
    k_bil_v<<<1, 128, 0, stream>>>(xp, bilW, v, 1.0f / (float)N);
    k_bil_out<<<(R + 127) / 128, 128, 0, stream>>>(v, y3, bilb, (float*)d_out, R);
  }
}